// Round 26
// baseline (59.425 us; speedup 1.0000x reference)
//
#include <hip/hip_runtime.h>
#include <hip/hip_bf16.h>

// Sizes fixed by the reference problem.
#define B_N   4096
#define D_N   1024
#define P_N   64
#define C0_N  16
#define C1_N  32
#define NC_N  48    // C0 + C1 concatenated

// fused parent geometry (r26): 512 blocks x 8 rows x FULL K, NO LDS staging
#define PRR   8      // rows per P block

// child GEMM K-split — KC2 MUST stay 8 (r14/r16: 16 writers/row -> ~30x HBM amp).
#define KC2   8
#define DKC2  128
#define TRC   64     // child MFMA row tile

// Tie physics: fp32 softmax probs can only tie when the true logit gap is
// <~2e-7. Trunc-split bf16 parent GEMM logit error ~1e-8 (dropped xl*wl and
// residual-of-residual are 2^-16 relative per product), so tau=1e-6 keeps
// ~100x margin; ~15-30 suspect rows total.
#define GAP_TAU 1e-6f
#define NEG_INF (-3.402823466e38f)

// Lessons (r10-r25): no grid.sync; no per-block device fences; LDS-staged
// serial K-chunk loops with barriers are stall-bound at low blocks/CU
// (r22/23/25: fused parent 41-62us, ~90% idle even warm-cache) -> r26 loads
// MFMA fragments DIRECTLY from global (L1/L2-resident), zero barriers in
// the K loop; child KC2=8 only; minimize dispatches (2-dispatch chain).

typedef __attribute__((ext_vector_type(8))) short short8v;
typedef __attribute__((ext_vector_type(4))) float f32x4;

static __device__ __forceinline__ unsigned f2bf(float f) {
    union { float f; unsigned u; } v; v.f = f;
    return (v.u + 0x7FFF + ((v.u >> 16) & 1)) >> 16;   // RNE, low 16 valid
}

// trunc-split 8 floats (2x float4) into hi/lo bf16 fragments (in-register).
static __device__ __forceinline__ void split8(float4 a, float4 b,
                                              short8v& h, short8v& l) {
    const float e[8] = {a.x, a.y, a.z, a.w, b.x, b.y, b.z, b.w};
    #pragma unroll
    for (int i = 0; i < 8; ++i) {
        union { float f; unsigned u; } t, s;
        t.f = e[i];
        const unsigned hu = t.u >> 16;        // trunc to bf16
        s.u = hu << 16;
        t.f = e[i] - s.f;                     // exact residual
        h[i] = (short)hu;
        l[i] = (short)(t.u >> 16);            // trunc residual to bf16
    }
}

// ===========================================================================
// P: fused parent — full-K MFMA logits via DIRECT global fragment loads
// (no LDS staging, no K-loop barriers) + route + fixup + c0/c1 zeroing.
// 512 blocks x 256 threads (4 waves). Block = 8 rows x 64 parents x K=1024.
// Lane l of wave wv loads A = x[r0+(lr&7)][kw] and B = pw[wv*16+lr][kw]
// (kw = ks*32 + lg*8, 8 floats = 2 float4 each), splits in-register, and
// issues 3 MFMA (ah*bh + al*bh + ah*bl), fp32 acc. 32 independent K-steps
// pipeline freely (x/pw are L1/L2-resident; pw = 256KB total). A-fragment
// rows 8-15 are duplicates of 0-7 (clamped) -> D rows 8-15 discarded.
// Route: logits->LDS(+pb), wave wv routes rows wv*2..wv*2+1; pclass[row]
// only (no atomics). Near-ties -> block-cooperative f64 softmax emulation
// (first-index argmax on fp32-quantized probs). Zeroes 384-float c0/c1 slice.
// ===========================================================================
__global__ __launch_bounds__(256, 4)
void hc_parent_fused(const float* __restrict__ x,
                     const float* __restrict__ pw,
                     const float* __restrict__ pb,
                     float* __restrict__ out_logits,
                     float* __restrict__ out_cz,      // = out_c0 (contig c0|c1)
                     int* __restrict__ pclass) {
    __shared__ float  llds[PRR][68];
    __shared__ double ld[P_N];
    __shared__ int    sq[PRR];
    __shared__ int    sqn;

    const int tid = threadIdx.x;
    const int r0  = blockIdx.x * PRR;

    if (tid == 0) sqn = 0;
    // zero this block's c0/c1 slice: 8 rows x 48 = 384 floats = 96 float4
    if (tid < 96)
        ((float4*)(out_cz + (size_t)blockIdx.x * (PRR * NC_N)))[tid] =
            make_float4(0.f, 0.f, 0.f, 0.f);

    const int lane = tid & 63;
    const int wv   = tid >> 6;     // 0..3 = parent tile
    const int lr   = lane & 15;
    const int lg   = lane >> 4;

    const float* xbase = &x[(size_t)(r0 + (lr & 7)) * D_N + lg * 8];
    const float* wbase = &pw[(size_t)(wv * 16 + lr) * D_N + lg * 8];

    f32x4 acc = {0.f, 0.f, 0.f, 0.f};
    #pragma unroll 4
    for (int ks = 0; ks < 32; ++ks) {
        const float4 xa = *(const float4*)&xbase[ks * 32];
        const float4 xb = *(const float4*)&xbase[ks * 32 + 4];
        const float4 wa = *(const float4*)&wbase[ks * 32];
        const float4 wb = *(const float4*)&wbase[ks * 32 + 4];
        short8v ah, al, bh, bl;
        split8(xa, xb, ah, al);
        split8(wa, wb, bh, bl);
        acc = __builtin_amdgcn_mfma_f32_16x16x32_bf16(ah, bh, acc, 0, 0, 0);
        acc = __builtin_amdgcn_mfma_f32_16x16x32_bf16(al, bh, acc, 0, 0, 0);
        acc = __builtin_amdgcn_mfma_f32_16x16x32_bf16(ah, bl, acc, 0, 0, 0);
    }

    // D layout (m89-validated): x-row = lg*4+reg, parent = wv*16+lr.
    // Only lg<2 lanes hold real rows (0..7); rows 8-15 are clamp duplicates.
    if (lg < 2) {
        #pragma unroll
        for (int reg = 0; reg < 4; ++reg)
            llds[lg * 4 + reg][wv * 16 + lr] = acc[reg];
    }
    __syncthreads();

    // ---- route: wave wv handles rows wv*2, wv*2+1 ----
    const int p = lane;
    #pragma unroll
    for (int rq = 0; rq < 2; ++rq) {
        const int rloc = wv * 2 + rq;
        const int row  = r0 + rloc;
        const float l  = llds[rloc][p] + pb[p];
        out_logits[(size_t)row * P_N + p] = l;

        float m1 = l; int i1 = p; float m2 = NEG_INF;
        #pragma unroll
        for (int off = 32; off > 0; off >>= 1) {
            const float om1 = __shfl_xor(m1, off);
            const int   oi1 = __shfl_xor(i1, off);
            const float om2 = __shfl_xor(m2, off);
            if (om1 > m1 || (om1 == m1 && oi1 < i1)) {
                m2 = fmaxf(m1, om2); m1 = om1; i1 = oi1;
            } else m2 = fmaxf(m2, om1);
        }
        if (p == 0) {
            if (m1 - m2 > GAP_TAU) {
                pclass[row] = i1;                 // no atomics
            } else {
                const int q = atomicAdd(&sqn, 1); // LDS only
                sq[q] = row;
            }
        }
    }
    __syncthreads();

    const int nq = sqn;
    if (nq == 0) return;    // uniform across the block

    // ---- block-cooperative f64 fixup (~26 suspect rows chip-wide) ----
    for (int qi = 0; qi < nq; ++qi) {
        const int srow = sq[qi];
        const float* xr = &x[(size_t)srow * D_N + p * 16];
        float4 xv[4];
        #pragma unroll
        for (int k = 0; k < 4; ++k) xv[k] = *(const float4*)&xr[k * 4];

        #pragma unroll 2
        for (int pass = 0; pass < 16; ++pass) {
            const int pp = wv * 16 + pass;
            const float* wr = &pw[(size_t)pp * D_N + p * 16];
            double a0 = 0.0, a1 = 0.0, a2 = 0.0, a3 = 0.0;
            #pragma unroll
            for (int k = 0; k < 4; ++k) {
                const float4 wv2 = *(const float4*)&wr[k * 4];
                a0 = fma((double)wv2.x, (double)xv[k].x, a0);
                a1 = fma((double)wv2.y, (double)xv[k].y, a1);
                a2 = fma((double)wv2.z, (double)xv[k].z, a2);
                a3 = fma((double)wv2.w, (double)xv[k].w, a3);
            }
            double a = (a0 + a1) + (a2 + a3);
            #pragma unroll
            for (int off = 32; off > 0; off >>= 1) a += __shfl_xor(a, off);
            if (p == 0) ld[pp] = a;
        }
        __syncthreads();

        if (wv == 0) {
            const double accv = (double)pb[p] + ld[p];
            const float  l32  = (float)accv;
            float m = l32;
            #pragma unroll
            for (int off = 32; off > 0; off >>= 1)
                m = fmaxf(m, __shfl_xor(m, off));
            const float e = (float)exp((double)(l32 - m));  // correctly-rounded
            double es = (double)e;
            #pragma unroll
            for (int off = 32; off > 0; off >>= 1) es += __shfl_xor(es, off);
            es = __shfl(es, 0);
            const float s    = (float)es;
            const float prob = e / s;    // IEEE f32 divide: ties survive
            float pm = prob; int pi = p;
            #pragma unroll
            for (int off = 32; off > 0; off >>= 1) {
                const float opm = __shfl_xor(pm, off);
                const int   opi = __shfl_xor(pi, off);
                if (opm > pm || (opm == pm && opi < pi)) { pm = opm; pi = opi; }
            }
            if (p == 0) pclass[srow] = pi;
        }
        __syncthreads();
    }
}

// ===========================================================================
// C: child GEMM via bf16 MFMA + per-block pclass scan (proven r25).
// Grid (64 classes, 8 kc, 3 slots of 64 rows); every block scans pclass
// (16KB) + 8-step Hillis-Steele -> deterministic row-ascending list, then
// ghost slots exit. MFMA tile 64 rows x 48 outs x K=128; atomicAdd epilogue
// onto P-zeroed outputs, bias folded at kc==0. LDS ~30KB -> 5 blocks/CU.
// UNCHANGED from r25.
// ===========================================================================
__global__ __launch_bounds__(256, 5)
void hc_child_mfma(const float* __restrict__ x,
                   const float* __restrict__ w0,
                   const float* __restrict__ w1,
                   const float* __restrict__ b0,
                   const float* __restrict__ b1,
                   const int* __restrict__ pclass,
                   float* __restrict__ out_c0,
                   float* __restrict__ out_c1) {
    const int c  = blockIdx.x;
    const int kc = blockIdx.y;
    const int t0 = blockIdx.z * TRC;
    const int d0 = kc * DKC2;

    __shared__ int            scnt[256];
    __shared__ int            slist[TRC];
    __shared__ unsigned short xs[16][TRC][8];    // [kchunk][row][8k] bf16
    __shared__ unsigned short ws[16][NC_N][8];   // [kchunk][out][8k] bf16

    const int tid = threadIdx.x;

    // ---- scan pclass: count + prefix-sum + compact this slot's window ----
    const int rbase = tid * 16;
    int myc = 0;
    #pragma unroll
    for (int k = 0; k < 16; ++k)
        myc += (pclass[rbase + k] == c) ? 1 : 0;
    scnt[tid] = myc;
    __syncthreads();
    for (int off = 1; off < 256; off <<= 1) {     // inclusive Hillis-Steele
        const int v = scnt[tid];
        const int u = (tid >= off) ? scnt[tid - off] : 0;
        __syncthreads();
        scnt[tid] = v + u;
        __syncthreads();
    }
    const int excl = scnt[tid] - myc;
    const int n    = scnt[255];
    if (t0 >= n) return;                          // uniform ghost-slot exit
    const int m = min(TRC, n - t0);
    {
        int pos = excl;
        #pragma unroll
        for (int k = 0; k < 16; ++k) {
            const int row = rbase + k;
            if (pclass[row] == c) {
                const int rel = pos - t0;
                if (rel >= 0 && rel < TRC) slist[rel] = row;
                ++pos;
            }
        }
    }
    __syncthreads();                              // slist complete

    // ---- stage weights: 48 rows x 128 floats ----
    #pragma unroll
    for (int k = 0; k < 6; ++k) {
        const int f = tid + 256 * k, j = f >> 5, c4 = (f & 31) * 4;
        const float* src = (j < C0_N)
            ? &w0[((size_t)c * C0_N + j) * D_N + d0 + c4]
            : &w1[((size_t)c * C1_N + (j - C0_N)) * D_N + d0 + c4];
        const float4 v = *(const float4*)src;
        unsigned short* dst = &ws[c4 >> 3][j][c4 & 4];
        dst[0] = (unsigned short)f2bf(v.x); dst[1] = (unsigned short)f2bf(v.y);
        dst[2] = (unsigned short)f2bf(v.z); dst[3] = (unsigned short)f2bf(v.w);
    }
    // ---- stage gathered x rows: 64 rows x 128 floats ----
    #pragma unroll
    for (int k = 0; k < 8; ++k) {
        const int f = tid + 256 * k, r = f >> 5, c4 = (f & 31) * 4;
        const int row = slist[r < m ? r : 0];
        const float4 v = *(const float4*)&x[(size_t)row * D_N + d0 + c4];
        unsigned short* dst = &xs[c4 >> 3][r][c4 & 4];
        dst[0] = (unsigned short)f2bf(v.x); dst[1] = (unsigned short)f2bf(v.y);
        dst[2] = (unsigned short)f2bf(v.z); dst[3] = (unsigned short)f2bf(v.w);
    }
    __syncthreads();

    const int lane = tid & 63;
    const int wv   = tid >> 6;
    const int lr   = lane & 15;
    const int lg   = lane >> 4;

    f32x4 acc0 = {0.f, 0.f, 0.f, 0.f};
    f32x4 acc1 = {0.f, 0.f, 0.f, 0.f};
    f32x4 acc2 = {0.f, 0.f, 0.f, 0.f};
    #pragma unroll
    for (int ks = 0; ks < 4; ++ks) {
        const int kq = ks * 4 + lg;
        const short8v a  = *(const short8v*)&xs[kq][wv * 16 + lr][0];
        const short8v bA = *(const short8v*)&ws[kq][lr][0];
        const short8v bB = *(const short8v*)&ws[kq][16 + lr][0];
        const short8v bC = *(const short8v*)&ws[kq][32 + lr][0];
        acc0 = __builtin_amdgcn_mfma_f32_16x16x32_bf16(a, bA, acc0, 0, 0, 0);
        acc1 = __builtin_amdgcn_mfma_f32_16x16x32_bf16(a, bB, acc1, 0, 0, 0);
        acc2 = __builtin_amdgcn_mfma_f32_16x16x32_bf16(a, bC, acc2, 0, 0, 0);
    }

    #pragma unroll
    for (int reg = 0; reg < 4; ++reg) {
        const int rr = wv * 16 + lg * 4 + reg;
        if (rr < m) {
            const int row = slist[rr];
            #pragma unroll
            for (int nt = 0; nt < 3; ++nt) {
                const int jj = nt * 16 + lr;
                float v = (nt == 0) ? acc0[reg] : (nt == 1) ? acc1[reg] : acc2[reg];
                if (kc == 0)
                    v += (jj < C0_N) ? b0[c * C0_N + jj]
                                     : b1[c * C1_N + (jj - C0_N)];
                if (jj < C0_N)
                    atomicAdd(&out_c0[(size_t)row * C0_N + jj], v);
                else
                    atomicAdd(&out_c1[(size_t)row * C1_N + (jj - C0_N)], v);
            }
        }
    }
}

// ---------------------------------------------------------------------------
extern "C" void kernel_launch(void* const* d_in, const int* in_sizes, int n_in,
                              void* d_out, int out_size, void* d_ws, size_t ws_size,
                              hipStream_t stream) {
    const float* x  = (const float*)d_in[0];
    const float* pw = (const float*)d_in[1];
    const float* pb = (const float*)d_in[2];
    const float* w0 = (const float*)d_in[3];
    const float* b0 = (const float*)d_in[4];
    const float* w1 = (const float*)d_in[5];
    const float* b1 = (const float*)d_in[6];

    float* out_logits = (float*)d_out;                       // [4096][64]
    float* out_c0     = out_logits + (size_t)B_N * P_N;      // [4096][16]
    float* out_c1     = out_c0     + (size_t)B_N * C0_N;     // [4096][32]

    // ws: [pclass 4096 ints] — that's all.
    int* pclass = (int*)d_ws;

    hc_parent_fused<<<B_N / PRR, 256, 0, stream>>>(
        x, pw, pb, out_logits, out_c0, pclass);

    hc_child_mfma<<<dim3(P_N, KC2, 3), 256, 0, stream>>>(
        x, w0, w1, b0, b1, pclass, out_c0, out_c1);
}

// Round 27
// 44.524 us; speedup vs baseline: 1.3347x; 1.3347x over previous
//
#include <hip/hip_runtime.h>
#include <hip/hip_bf16.h>

// Sizes fixed by the reference problem.
#define B_N   4096
#define D_N   1024
#define P_N   64
#define C0_N  16
#define C1_N  32
#define NC_N  48    // C0 + C1 concatenated

// fused parent geometry (r25-proven): 512 blocks x 8 rows x FULL K
#define PRR   8      // rows per P block
#define PKC   8      // serial K chunks
#define PDK   128    // chunk depth

// child GEMM K-split — KC2 MUST stay 8 (r14/r16: 16 writers/row -> ~30x HBM amp).
#define KC2   8
#define DKC2  128
#define TRC   64     // child MFMA row tile

// Tie physics: fp32 softmax probs can only tie when the true logit gap is
// <~2e-7. 3-pass bf16-split parent GEMM logit error ~2-3e-8, so tau=1e-6
// keeps ~25x margin; ~15-30 suspect rows total.
#define GAP_TAU 1e-6f
#define NEG_INF (-3.402823466e38f)

// Lessons (r10-r26): no grid.sync; no per-block device fences; direct-global
// MFMA fragments lose to LDS staging (r26: 52 vs 41.5us — 32B/lane gathers
// thrash L1); LDS kq-plane strides != 0 mod 128B; child KC2=8 only;
// 2-dispatch chain. r27: T14 software pipelining in P — prefetch chunk k+1
// into registers while chunk k's MFMAs run (loads fly across the barrier).

typedef __attribute__((ext_vector_type(8))) short short8v;
typedef __attribute__((ext_vector_type(4))) float f32x4;

static __device__ __forceinline__ unsigned f2bf(float f) {
    union { float f; unsigned u; } v; v.f = f;
    return (v.u + 0x7FFF + ((v.u >> 16) & 1)) >> 16;   // RNE, low 16 valid
}
// split float4 into packed-hi (2x uint) and packed-lo residual (2x uint)
static __device__ __forceinline__ void split4(float4 v, uint2& hp, uint2& lp) {
    const unsigned hx = f2bf(v.x), hy = f2bf(v.y);
    const unsigned hz = f2bf(v.z), hw = f2bf(v.w);
    union { unsigned u; float f; } t;
    float rx, ry, rz, rw;
    t.u = hx << 16; rx = v.x - t.f;
    t.u = hy << 16; ry = v.y - t.f;
    t.u = hz << 16; rz = v.z - t.f;
    t.u = hw << 16; rw = v.w - t.f;
    hp.x = hx | (hy << 16);             hp.y = hz | (hw << 16);
    lp.x = f2bf(rx) | (f2bf(ry) << 16); lp.y = f2bf(rz) | (f2bf(rw) << 16);
}

// ===========================================================================
// P: fused parent — full-K bf16-split MFMA logits + route + fixup + zeroing.
// r25 structure (512 blocks x 256 threads, 3/CU, padded k-major LDS) with
// r27's T14 pipeline: chunk k+1's 9 float4 loads are ISSUED right after the
// stage barrier, so their latency hides under chunk k's split+MFMA phase.
// Route writes pclass[row] only (no atomics); near-ties -> LDS queue ->
// block-cooperative f64 softmax emulation (first-index argmax on fp32-
// quantized probs). Zeroes this block's 384-float c0/c1 slice.
// ===========================================================================
__global__ __launch_bounds__(256, 3)
void hc_parent_fused(const float* __restrict__ x,
                     const float* __restrict__ pw,
                     const float* __restrict__ pb,
                     float* __restrict__ out_logits,
                     float* __restrict__ out_cz,      // = out_c0 (contig c0|c1)
                     int* __restrict__ pclass) {
    __shared__ unsigned short xh[16][17][8], xl[16][17][8];   // rows 8-15 pad
    __shared__ unsigned short wh[16][65][8], wl[16][65][8];
    __shared__ float  llds[PRR][68];
    __shared__ double ld[P_N];
    __shared__ int    sq[PRR];
    __shared__ int    sqn;

    const int tid = threadIdx.x;
    const int r0  = blockIdx.x * PRR;

    if (tid == 0) sqn = 0;
    // zero this block's c0/c1 slice: 8 rows x 48 = 384 floats = 96 float4
    if (tid < 96)
        ((float4*)(out_cz + (size_t)blockIdx.x * (PRR * NC_N)))[tid] =
            make_float4(0.f, 0.f, 0.f, 0.f);

    const int lane = tid & 63;
    const int wv   = tid >> 6;     // 0..3 = parent tile
    const int lr   = lane & 15;
    const int lg   = lane >> 4;

    // per-thread staging coordinates (fixed across chunks)
    const int sxr = tid >> 5;            // x stage row 0..7
    const int sxc = (tid & 31) * 4;      // x stage col
    f32x4 acc = {0.f, 0.f, 0.f, 0.f};

    // ---- prologue: load chunk 0 into registers ----
    float4 xreg;
    float4 wreg[8];
    xreg = *(const float4*)&x[(size_t)(r0 + sxr) * D_N + sxc];
    #pragma unroll
    for (int k = 0; k < 8; ++k) {
        const int f = tid + 256 * k, rr = f >> 5, cc = (f & 31) * 4;
        wreg[k] = *(const float4*)&pw[(size_t)rr * D_N + cc];
    }

    for (int kc = 0; kc < PKC; ++kc) {
        __syncthreads();               // prior chunk's LDS reads done
        // ---- split + write current chunk's registers to LDS ----
        {
            uint2 hp, lp; split4(xreg, hp, lp);
            *(uint2*)&xh[sxc >> 3][sxr][sxc & 4] = hp;
            *(uint2*)&xl[sxc >> 3][sxr][sxc & 4] = lp;
        }
        #pragma unroll
        for (int k = 0; k < 8; ++k) {
            const int f = tid + 256 * k, rr = f >> 5, cc = (f & 31) * 4;
            uint2 hp, lp; split4(wreg[k], hp, lp);
            *(uint2*)&wh[cc >> 3][rr][cc & 4] = hp;
            *(uint2*)&wl[cc >> 3][rr][cc & 4] = lp;
        }
        __syncthreads();               // LDS ready

        // ---- T14: issue next chunk's loads; they fly during the MFMAs ----
        if (kc + 1 < PKC) {
            const int d0n = (kc + 1) * PDK;
            xreg = *(const float4*)&x[(size_t)(r0 + sxr) * D_N + d0n + sxc];
            #pragma unroll
            for (int k = 0; k < 8; ++k) {
                const int f = tid + 256 * k, rr = f >> 5, cc = (f & 31) * 4;
                wreg[k] = *(const float4*)&pw[(size_t)rr * D_N + d0n + cc];
            }
        }

        // ---- MFMA on current chunk (reads LDS only) ----
        #pragma unroll
        for (int ks = 0; ks < 4; ++ks) {
            const int kq = ks * 4 + lg;
            const short8v ah = *(const short8v*)&xh[kq][lr][0];
            const short8v al = *(const short8v*)&xl[kq][lr][0];
            const short8v bh = *(const short8v*)&wh[kq][wv * 16 + lr][0];
            const short8v bl = *(const short8v*)&wl[kq][wv * 16 + lr][0];
            acc = __builtin_amdgcn_mfma_f32_16x16x32_bf16(ah, bh, acc, 0, 0, 0);
            acc = __builtin_amdgcn_mfma_f32_16x16x32_bf16(al, bh, acc, 0, 0, 0);
            acc = __builtin_amdgcn_mfma_f32_16x16x32_bf16(ah, bl, acc, 0, 0, 0);
        }
    }
    __syncthreads();
    // D layout (m89-validated): x-row = lg*4+reg, parent = wv*16+lr.
    // Only lg<2 lanes hold real rows (0..7); others are padding.
    if (lg < 2) {
        #pragma unroll
        for (int reg = 0; reg < 4; ++reg)
            llds[lg * 4 + reg][wv * 16 + lr] = acc[reg];
    }
    __syncthreads();

    // ---- route: wave wv handles rows wv*2, wv*2+1 ----
    const int p = lane;
    #pragma unroll
    for (int rq = 0; rq < 2; ++rq) {
        const int rloc = wv * 2 + rq;
        const int row  = r0 + rloc;
        const float l  = llds[rloc][p] + pb[p];
        out_logits[(size_t)row * P_N + p] = l;

        float m1 = l; int i1 = p; float m2 = NEG_INF;
        #pragma unroll
        for (int off = 32; off > 0; off >>= 1) {
            const float om1 = __shfl_xor(m1, off);
            const int   oi1 = __shfl_xor(i1, off);
            const float om2 = __shfl_xor(m2, off);
            if (om1 > m1 || (om1 == m1 && oi1 < i1)) {
                m2 = fmaxf(m1, om2); m1 = om1; i1 = oi1;
            } else m2 = fmaxf(m2, om1);
        }
        if (p == 0) {
            if (m1 - m2 > GAP_TAU) {
                pclass[row] = i1;                 // no atomics
            } else {
                const int q = atomicAdd(&sqn, 1); // LDS only
                sq[q] = row;
            }
        }
    }
    __syncthreads();

    const int nq = sqn;
    if (nq == 0) return;    // uniform across the block

    // ---- block-cooperative f64 fixup (~26 suspect rows chip-wide) ----
    for (int qi = 0; qi < nq; ++qi) {
        const int srow = sq[qi];
        const float* xr = &x[(size_t)srow * D_N + p * 16];
        float4 xv[4];
        #pragma unroll
        for (int k = 0; k < 4; ++k) xv[k] = *(const float4*)&xr[k * 4];

        #pragma unroll 2
        for (int pass = 0; pass < 16; ++pass) {
            const int pp = wv * 16 + pass;
            const float* wr = &pw[(size_t)pp * D_N + p * 16];
            double a0 = 0.0, a1 = 0.0, a2 = 0.0, a3 = 0.0;
            #pragma unroll
            for (int k = 0; k < 4; ++k) {
                const float4 wv2 = *(const float4*)&wr[k * 4];
                a0 = fma((double)wv2.x, (double)xv[k].x, a0);
                a1 = fma((double)wv2.y, (double)xv[k].y, a1);
                a2 = fma((double)wv2.z, (double)xv[k].z, a2);
                a3 = fma((double)wv2.w, (double)xv[k].w, a3);
            }
            double a = (a0 + a1) + (a2 + a3);
            #pragma unroll
            for (int off = 32; off > 0; off >>= 1) a += __shfl_xor(a, off);
            if (p == 0) ld[pp] = a;
        }
        __syncthreads();

        if (wv == 0) {
            const double accv = (double)pb[p] + ld[p];
            const float  l32  = (float)accv;
            float m = l32;
            #pragma unroll
            for (int off = 32; off > 0; off >>= 1)
                m = fmaxf(m, __shfl_xor(m, off));
            const float e = (float)exp((double)(l32 - m));  // correctly-rounded
            double es = (double)e;
            #pragma unroll
            for (int off = 32; off > 0; off >>= 1) es += __shfl_xor(es, off);
            es = __shfl(es, 0);
            const float s    = (float)es;
            const float prob = e / s;    // IEEE f32 divide: ties survive
            float pm = prob; int pi = p;
            #pragma unroll
            for (int off = 32; off > 0; off >>= 1) {
                const float opm = __shfl_xor(pm, off);
                const int   opi = __shfl_xor(pi, off);
                if (opm > pm || (opm == pm && opi < pi)) { pm = opm; pi = opi; }
            }
            if (p == 0) pclass[srow] = pi;
        }
        __syncthreads();
    }
}

// ===========================================================================
// C: child GEMM via bf16 MFMA + per-block pclass scan (proven r25).
// Grid (64 classes, 8 kc, 3 slots of 64 rows); every block scans pclass
// (16KB) + 8-step Hillis-Steele -> deterministic row-ascending list, then
// ghost slots exit. MFMA tile 64 rows x 48 outs x K=128; atomicAdd epilogue
// onto P-zeroed outputs, bias folded at kc==0. LDS ~30KB -> 5 blocks/CU.
// UNCHANGED from r25.
// ===========================================================================
__global__ __launch_bounds__(256, 5)
void hc_child_mfma(const float* __restrict__ x,
                   const float* __restrict__ w0,
                   const float* __restrict__ w1,
                   const float* __restrict__ b0,
                   const float* __restrict__ b1,
                   const int* __restrict__ pclass,
                   float* __restrict__ out_c0,
                   float* __restrict__ out_c1) {
    const int c  = blockIdx.x;
    const int kc = blockIdx.y;
    const int t0 = blockIdx.z * TRC;
    const int d0 = kc * DKC2;

    __shared__ int            scnt[256];
    __shared__ int            slist[TRC];
    __shared__ unsigned short xs[16][TRC][8];    // [kchunk][row][8k] bf16
    __shared__ unsigned short ws[16][NC_N][8];   // [kchunk][out][8k] bf16

    const int tid = threadIdx.x;

    // ---- scan pclass: count + prefix-sum + compact this slot's window ----
    const int rbase = tid * 16;
    int myc = 0;
    #pragma unroll
    for (int k = 0; k < 16; ++k)
        myc += (pclass[rbase + k] == c) ? 1 : 0;
    scnt[tid] = myc;
    __syncthreads();
    for (int off = 1; off < 256; off <<= 1) {     // inclusive Hillis-Steele
        const int v = scnt[tid];
        const int u = (tid >= off) ? scnt[tid - off] : 0;
        __syncthreads();
        scnt[tid] = v + u;
        __syncthreads();
    }
    const int excl = scnt[tid] - myc;
    const int n    = scnt[255];
    if (t0 >= n) return;                          // uniform ghost-slot exit
    const int m = min(TRC, n - t0);
    {
        int pos = excl;
        #pragma unroll
        for (int k = 0; k < 16; ++k) {
            const int row = rbase + k;
            if (pclass[row] == c) {
                const int rel = pos - t0;
                if (rel >= 0 && rel < TRC) slist[rel] = row;
                ++pos;
            }
        }
    }
    __syncthreads();                              // slist complete

    // ---- stage weights: 48 rows x 128 floats ----
    #pragma unroll
    for (int k = 0; k < 6; ++k) {
        const int f = tid + 256 * k, j = f >> 5, c4 = (f & 31) * 4;
        const float* src = (j < C0_N)
            ? &w0[((size_t)c * C0_N + j) * D_N + d0 + c4]
            : &w1[((size_t)c * C1_N + (j - C0_N)) * D_N + d0 + c4];
        const float4 v = *(const float4*)src;
        unsigned short* dst = &ws[c4 >> 3][j][c4 & 4];
        dst[0] = (unsigned short)f2bf(v.x); dst[1] = (unsigned short)f2bf(v.y);
        dst[2] = (unsigned short)f2bf(v.z); dst[3] = (unsigned short)f2bf(v.w);
    }
    // ---- stage gathered x rows: 64 rows x 128 floats ----
    #pragma unroll
    for (int k = 0; k < 8; ++k) {
        const int f = tid + 256 * k, r = f >> 5, c4 = (f & 31) * 4;
        const int row = slist[r < m ? r : 0];
        const float4 v = *(const float4*)&x[(size_t)row * D_N + d0 + c4];
        unsigned short* dst = &xs[c4 >> 3][r][c4 & 4];
        dst[0] = (unsigned short)f2bf(v.x); dst[1] = (unsigned short)f2bf(v.y);
        dst[2] = (unsigned short)f2bf(v.z); dst[3] = (unsigned short)f2bf(v.w);
    }
    __syncthreads();

    const int lane = tid & 63;
    const int wv   = tid >> 6;
    const int lr   = lane & 15;
    const int lg   = lane >> 4;

    f32x4 acc0 = {0.f, 0.f, 0.f, 0.f};
    f32x4 acc1 = {0.f, 0.f, 0.f, 0.f};
    f32x4 acc2 = {0.f, 0.f, 0.f, 0.f};
    #pragma unroll
    for (int ks = 0; ks < 4; ++ks) {
        const int kq = ks * 4 + lg;
        const short8v a  = *(const short8v*)&xs[kq][wv * 16 + lr][0];
        const short8v bA = *(const short8v*)&ws[kq][lr][0];
        const short8v bB = *(const short8v*)&ws[kq][16 + lr][0];
        const short8v bC = *(const short8v*)&ws[kq][32 + lr][0];
        acc0 = __builtin_amdgcn_mfma_f32_16x16x32_bf16(a, bA, acc0, 0, 0, 0);
        acc1 = __builtin_amdgcn_mfma_f32_16x16x32_bf16(a, bB, acc1, 0, 0, 0);
        acc2 = __builtin_amdgcn_mfma_f32_16x16x32_bf16(a, bC, acc2, 0, 0, 0);
    }

    #pragma unroll
    for (int reg = 0; reg < 4; ++reg) {
        const int rr = wv * 16 + lg * 4 + reg;
        if (rr < m) {
            const int row = slist[rr];
            #pragma unroll
            for (int nt = 0; nt < 3; ++nt) {
                const int jj = nt * 16 + lr;
                float v = (nt == 0) ? acc0[reg] : (nt == 1) ? acc1[reg] : acc2[reg];
                if (kc == 0)
                    v += (jj < C0_N) ? b0[c * C0_N + jj]
                                     : b1[c * C1_N + (jj - C0_N)];
                if (jj < C0_N)
                    atomicAdd(&out_c0[(size_t)row * C0_N + jj], v);
                else
                    atomicAdd(&out_c1[(size_t)row * C1_N + (jj - C0_N)], v);
            }
        }
    }
}

// ---------------------------------------------------------------------------
extern "C" void kernel_launch(void* const* d_in, const int* in_sizes, int n_in,
                              void* d_out, int out_size, void* d_ws, size_t ws_size,
                              hipStream_t stream) {
    const float* x  = (const float*)d_in[0];
    const float* pw = (const float*)d_in[1];
    const float* pb = (const float*)d_in[2];
    const float* w0 = (const float*)d_in[3];
    const float* b0 = (const float*)d_in[4];
    const float* w1 = (const float*)d_in[5];
    const float* b1 = (const float*)d_in[6];

    float* out_logits = (float*)d_out;                       // [4096][64]
    float* out_c0     = out_logits + (size_t)B_N * P_N;      // [4096][16]
    float* out_c1     = out_c0     + (size_t)B_N * C0_N;     // [4096][32]

    // ws: [pclass 4096 ints] — that's all.
    int* pclass = (int*)d_ws;

    hc_parent_fused<<<B_N / PRR, 256, 0, stream>>>(
        x, pw, pb, out_logits, out_c0, pclass);

    hc_child_mfma<<<dim3(P_N, KC2, 3), 256, 0, stream>>>(
        x, w0, w1, b0, b1, pclass, out_c0, out_c1);
}